// Round 1
// baseline (165.755 us; speedup 1.0000x reference)
//
#include <hip/hip_runtime.h>
#include <math.h>

#define L_   8192
#define D_   512
#define E_   8
#define DE_  4096        // D_*E_
#define C_   256         // number of L-chunks
#define LC_  32          // chunk length = L_/C_
#define TD_  128         // d-span per block (D_/4)
#define NF4_ (LC_ * TD_ / 4)   // f4 elements in an LDS tile = 1024 (16 KB)
#define P2B_ 64          // pass2 block size

typedef float f4_t __attribute__((ext_vector_type(4)));

__device__ __forceinline__ float sigmoidf_(float v) {
    return 1.0f / (1.0f + expf(-v));
}

// ---------------------------------------------------------------------------
// Pass 1: per (chunk c, d-quarter q) block. Stage the 32x128 x-tile into LDS
// once (coalesced f4 loads, single vmcnt drain), then compute the chunk-local
// contribution with zero inbound state:
//   s[e] = sum_i b^(LC-1-i) * a * x[c*LC+i, d]
// Inner loop reads LDS only (lgkmcnt domain) -> no store/load vmcnt mixing.
// ---------------------------------------------------------------------------
__global__ __launch_bounds__(256) void ema_pass1(const float* __restrict__ x,
                                                 const float* __restrict__ ld,
                                                 float* __restrict__ contrib) {
    __shared__ f4_t tile[NF4_];          // [32 rows][32 f4] = [32][128 floats]
    const int c = blockIdx.x >> 2;
    const int q = blockIdx.x & 3;
    const int t = threadIdx.x;

    // stage: 1024 f4 loads, 4 per thread; each wave covers 2 rows x 512 B
    const f4_t* xg = (const f4_t*)(x + (size_t)c * LC_ * D_ + q * TD_);
#pragma unroll
    for (int k = 0; k < 4; ++k) {
        const int i = t + 256 * k;                       // 0..1023
        tile[i] = xg[(size_t)(i >> 5) * (D_ / 4) + (i & 31)];
    }

    const int g  = (q << 8) + t;          // global group 0..1023
    const int dl = t >> 1;                // local d in [0,128)
    const int eb = (g & 1) << 2;          // e-block 0 or 4
    float a[4], b[4];
#pragma unroll
    for (int e = 0; e < 4; ++e) { a[e] = sigmoidf_(ld[eb + e]); b[e] = 1.0f - a[e]; }

    __syncthreads();

    const float* tl = (const float*)tile;
    float s[4] = {0.f, 0.f, 0.f, 0.f};
#pragma unroll
    for (int r = 0; r < LC_; ++r) {
        const float xv = tl[r * TD_ + dl];   // 2-lane broadcast, conflict-free
#pragma unroll
        for (int e = 0; e < 4; ++e) s[e] = fmaf(b[e], s[e], a[e] * xv);
    }
    f4_t rr = {s[0], s[1], s[2], s[3]};
    *(f4_t*)(contrib + (size_t)c * DE_ + 4 * g) = rr;
}

// ---------------------------------------------------------------------------
// Pass 2: per chain (d,e), scan the 256 chunk contributions.
// states[0] = x[0,d]; states[c+1] = (1-a)^LC * states[c] + contrib[c]
// states has C_+1 rows so the last store needs no guard.
// 64-thread blocks -> 64 blocks spread over 64 CUs; 32-wide prefetch stages.
// ---------------------------------------------------------------------------
__global__ __launch_bounds__(P2B_) void ema_pass2(const float* __restrict__ x,
                                                  const float* __restrict__ ld,
                                                  const float* __restrict__ contrib,
                                                  float* __restrict__ states) {
    const int chain = blockIdx.x * P2B_ + threadIdx.x;   // 0..4095
    const int d = chain >> 3;
    const int e = chain & 7;
    const float a = sigmoidf_(ld[e]);
    float B = 1.0f - a;
#pragma unroll
    for (int k = 0; k < 5; ++k) B *= B;   // (1-a)^32

    float cb[2][32];
#pragma unroll
    for (int j = 0; j < 32; ++j) cb[0][j] = contrib[(size_t)j * DE_ + chain];

    float s = x[d];                        // initial carry = x[0, d]
    states[chain] = s;

#pragma unroll
    for (int gr = 0; gr < C_ / 32; ++gr) {
        if (gr + 1 < C_ / 32) {
#pragma unroll
            for (int j = 0; j < 32; ++j)
                cb[(gr + 1) & 1][j] = contrib[(size_t)((gr + 1) * 32 + j) * DE_ + chain];
        }
#pragma unroll
        for (int j = 0; j < 32; ++j) {
            s = fmaf(B, s, cb[gr & 1][j]);
            states[(size_t)(gr * 32 + j + 1) * DE_ + chain] = s;
        }
    }
}

// ---------------------------------------------------------------------------
// Pass 3: replay each chunk from its correct inbound state, stream output.
// x-tile staged into LDS once (before any store is issued); the inner loop
// reads LDS + issues nontemporal f4 stores that are never waited on ->
// the 128 MB write stream runs unimpeded by load waits.
// ---------------------------------------------------------------------------
__global__ __launch_bounds__(256) void ema_pass3(const float* __restrict__ x,
                                                 const float* __restrict__ ld,
                                                 const float* __restrict__ states,
                                                 float* __restrict__ out) {
    __shared__ f4_t tile[NF4_];
    const int c = blockIdx.x >> 2;
    const int q = blockIdx.x & 3;
    const int t = threadIdx.x;

    const f4_t* xg = (const f4_t*)(x + (size_t)c * LC_ * D_ + q * TD_);
#pragma unroll
    for (int k = 0; k < 4; ++k) {
        const int i = t + 256 * k;
        tile[i] = xg[(size_t)(i >> 5) * (D_ / 4) + (i & 31)];
    }

    const int g  = (q << 8) + t;
    const int dl = t >> 1;
    const int eb = (g & 1) << 2;
    float a[4], b[4];
#pragma unroll
    for (int e = 0; e < 4; ++e) { a[e] = sigmoidf_(ld[eb + e]); b[e] = 1.0f - a[e]; }

    f4_t y = *(const f4_t*)(states + (size_t)c * DE_ + 4 * g);
    float* op = out + (size_t)c * LC_ * DE_ + 4 * g;

    __syncthreads();

    const float* tl = (const float*)tile;
#pragma unroll
    for (int r = 0; r < LC_; ++r) {
        const float xv = tl[r * TD_ + dl];
        y.x = fmaf(b[0], y.x, a[0] * xv);
        y.y = fmaf(b[1], y.y, a[1] * xv);
        y.z = fmaf(b[2], y.z, a[2] * xv);
        y.w = fmaf(b[3], y.w, a[3] * xv);
        __builtin_nontemporal_store(y, (f4_t*)(op + (size_t)r * DE_));
    }
}

// Fallback if workspace is too small: one thread per chain, full serial scan.
__global__ __launch_bounds__(256) void ema_naive(const float* __restrict__ x,
                                                 const float* __restrict__ ld,
                                                 float* __restrict__ out) {
    const int chain = blockIdx.x * 256 + threadIdx.x;  // 0..4095
    const int d = chain >> 3;
    const int e = chain & 7;
    const float a = sigmoidf_(ld[e]);
    const float b = 1.0f - a;
    float y = x[d];
    for (int l = 0; l < L_; ++l) {
        y = fmaf(b, y, a * x[(size_t)l * D_ + d]);
        out[(size_t)l * DE_ + chain] = y;
    }
}

extern "C" void kernel_launch(void* const* d_in, const int* in_sizes, int n_in,
                              void* d_out, int out_size, void* d_ws, size_t ws_size,
                              hipStream_t stream) {
    const float* x  = (const float*)d_in[0];
    const float* ld = (const float*)d_in[1];
    float* out = (float*)d_out;

    // contrib: C_ rows; states: C_+1 rows (extra row = unguarded last store)
    const size_t need = (size_t)(2 * C_ + 1) * DE_ * sizeof(float);
    if (ws_size >= need) {
        float* contrib = (float*)d_ws;
        float* states  = contrib + (size_t)C_ * DE_;
        ema_pass1<<<C_ * 4, 256, 0, stream>>>(x, ld, contrib);
        ema_pass2<<<DE_ / P2B_, P2B_, 0, stream>>>(x, ld, contrib, states);
        ema_pass3<<<C_ * 4, 256, 0, stream>>>(x, ld, states, out);
    } else {
        ema_naive<<<DE_ / 256, 256, 0, stream>>>(x, ld, out);
    }
}